// Round 7
// baseline (229.521 us; speedup 1.0000x reference)
//
#include <hip/hip_runtime.h>

typedef __attribute__((ext_vector_type(8))) short bf16x8;
typedef __attribute__((ext_vector_type(4))) float f32x4;

#define MFMA16(a, b, c) __builtin_amdgcn_mfma_f32_16x16x32_bf16(a, b, c, 0, 0, 0)

__device__ inline short f2bf(float f) {
  union { float f; unsigned u; } v;
  v.f = f;
  unsigned r = v.u + 0x7FFF + ((v.u >> 16) & 1);
  return (short)(r >> 16);
}
__device__ inline float bf2f(short s) {
  union { unsigned u; float f; } v;
  v.u = ((unsigned)(unsigned short)s) << 16;
  return v.f;
}
#define GLD_LDS16(g, l)                                                        \
  __builtin_amdgcn_global_load_lds(                                            \
      (const __attribute__((address_space(1))) unsigned int*)(g),              \
      (__attribute__((address_space(3))) unsigned int*)(l), 16, 0, 0)

__device__ __forceinline__ void raw_barrier() {
  __asm__ volatile("" ::: "memory");
  __builtin_amdgcn_s_barrier();
  __asm__ volatile("" ::: "memory");
}

// ---------------- prep: x->bf16 convert + all 4 weight transposes, one launch ----------------
__global__ __launch_bounds__(256) void prep_kernel(
    const float* __restrict__ x, const float* __restrict__ q_w,
    const float* __restrict__ k_w, const float* __restrict__ v_w,
    const float* __restrict__ o_w, short* __restrict__ xb,
    short* __restrict__ wqkv_t, short* __restrict__ wo_t) {
  __shared__ float t[64][65];
  int bid = blockIdx.x;
  if (bid < 4096) {  // cvt x
    int i = (bid * 256 + threadIdx.x) * 4;
    float4 f = *(const float4*)&x[i];
    short4 o;
    o.x = f2bf(f.x); o.y = f2bf(f.y); o.z = f2bf(f.z); o.w = f2bf(f.w);
    *(short4*)&xb[i] = o;
    return;
  }
  bid -= 4096;
  const float* src;
  short* dst;
  int C, bx, by;
  if (bid < 1024) {
    src = q_w; dst = wqkv_t; C = 2048;
    bx = (bid & 31) * 64; by = (bid >> 5) * 64;
  } else if (bid < 1152) {
    bid -= 1024;
    src = k_w; dst = wqkv_t + (size_t)2048 * 2048; C = 256;
    bx = (bid & 3) * 64; by = (bid >> 2) * 64;
  } else if (bid < 1280) {
    bid -= 1152;
    src = v_w; dst = wqkv_t + (size_t)2304 * 2048; C = 256;
    bx = (bid & 3) * 64; by = (bid >> 2) * 64;
  } else {
    bid -= 1280;
    src = o_w; dst = wo_t; C = 2048;
    bx = (bid & 31) * 64; by = (bid >> 5) * 64;
  }
  const int R = 2048;
  const int tx = threadIdx.x & 15;
  const int ty = threadIdx.x >> 4;
#pragma unroll
  for (int i = 0; i < 4; i++) {
    int row = ty + i * 16;
    float4 f = *(const float4*)&src[(size_t)(by + row) * C + bx + tx * 4];
    t[row][tx * 4 + 0] = f.x;
    t[row][tx * 4 + 1] = f.y;
    t[row][tx * 4 + 2] = f.z;
    t[row][tx * 4 + 3] = f.w;
  }
  __syncthreads();
#pragma unroll
  for (int i = 0; i < 4; i++) {
    int c = ty + i * 16;
    short4 o;
    o.x = f2bf(t[tx * 4 + 0][c]);
    o.y = f2bf(t[tx * 4 + 1][c]);
    o.z = f2bf(t[tx * 4 + 2][c]);
    o.w = f2bf(t[tx * 4 + 3][c]);
    *(short4*)&dst[(size_t)(bx + c) * R + by + tx * 4] = o;
  }
}

// ---------------- bf16 GEMM, 128x128 tile (m97-style), ring-4, split-K x2 -----------------
// Per iteration: 128 MFMA/wave (~1240cy) covers the HBM latency of loads issued one
// iteration earlier (vmcnt(8) counted ring). Conflict-free swizzle as in the 64-tile:
// source col pre-XOR ((r>>1)&3), read XOR (l16>>1)&3. Split-K x2 -> 640 blocks.
__global__ __launch_bounds__(256) void gemm128_kernel(const short* __restrict__ A,
                                                      const short* __restrict__ B,
                                                      float* __restrict__ C,
                                                      float* __restrict__ C2, int N,
                                                      int gx, int gy, int P) {
  __shared__ __align__(16) short As[4][128 * 32];
  __shared__ __align__(16) short Bs[4][128 * 32];
  int bid = blockIdx.x;
  const int gxy = gx * gy;
  int half = 0;
  if (bid >= gxy) { half = 1; bid -= gxy; }
  float* __restrict__ Cw = half ? C2 : C;
  const short* __restrict__ Ab = A + half * (P * 64);
  const short* __restrict__ Bb = B + half * (P * 64);
  const int xcd = bid & 7, idx = bid >> 3;
  const int colsPerX = gx >> 1, rowsPerX = gy >> 2;
  const int xt = (xcd & 1) * colsPerX + idx % colsPerX;
  const int yt = (xcd >> 1) * rowsPerX + idx / colsPerX;
  const int tid = threadIdx.x;
  const int lane = tid & 63, wave = tid >> 6;
  const int quad = lane >> 4, l16 = lane & 15;
  const int m0 = yt * 128, n0 = xt * 128;
  const int wm = (wave >> 1) * 64, wn = (wave & 1) * 64;
  const int r0 = tid >> 2, c0 = (tid & 3) * 8;               // LDS dest: linear
  const int ca = ((tid & 3) ^ ((r0 >> 1) & 3)) * 8;          // pre-swizzled source col
  const size_t arow0 = (size_t)(m0 + r0) * 2048, arow1 = (size_t)(m0 + r0 + 64) * 2048;
  const size_t brow0 = (size_t)(n0 + r0) * 2048, brow1 = (size_t)(n0 + r0 + 64) * 2048;
  f32x4 acc[4][4];
#pragma unroll
  for (int mi = 0; mi < 4; mi++)
#pragma unroll
    for (int ni = 0; ni < 4; ni++) acc[mi][ni] = (f32x4){0.f, 0.f, 0.f, 0.f};

#pragma unroll
  for (int st = 0; st < 4; st++) {
    const int kk = st * 32 + ca;
    GLD_LDS16(&Ab[arow0 + kk], &As[st][r0 * 32 + c0]);
    GLD_LDS16(&Ab[arow1 + kk], &As[st][(r0 + 64) * 32 + c0]);
    GLD_LDS16(&Bb[brow0 + kk], &Bs[st][r0 * 32 + c0]);
    GLD_LDS16(&Bb[brow1 + kk], &Bs[st][(r0 + 64) * 32 + c0]);
  }

  const int sx = (l16 >> 1) & 3;  // read XOR ((row>>1)&3 == (l16>>1)&3 for all frag rows)
  for (int p = 0; p < P; p++) {
    if (p < P - 1) {
      __asm__ volatile("s_waitcnt vmcnt(8)" ::: "memory");
    } else {
      __asm__ volatile("s_waitcnt vmcnt(0)" ::: "memory");
    }
    raw_barrier();
#pragma unroll
    for (int j = 0; j < 2; j++) {
      const int cur = (2 * p + j) & 3;
      bf16x8 af[4], bfr[4];
#pragma unroll
      for (int mi = 0; mi < 4; mi++)
        af[mi] = *(const bf16x8*)&As[cur][(wm + mi * 16 + l16) * 32 + ((quad ^ sx) * 8)];
#pragma unroll
      for (int ni = 0; ni < 4; ni++)
        bfr[ni] = *(const bf16x8*)&Bs[cur][(wn + ni * 16 + l16) * 32 + ((quad ^ sx) * 8)];
#pragma unroll
      for (int mi = 0; mi < 4; mi++)
#pragma unroll
        for (int ni = 0; ni < 4; ni++)
          acc[mi][ni] = MFMA16(af[mi], bfr[ni], acc[mi][ni]);
    }
    __asm__ volatile("s_waitcnt lgkmcnt(0)" ::: "memory");
    raw_barrier();
    if (p < P - 2) {
#pragma unroll
      for (int j = 0; j < 2; j++) {
        const int st = 2 * p + 4 + j;
        const int slot = st & 3;
        const int kk = st * 32 + ca;
        GLD_LDS16(&Ab[arow0 + kk], &As[slot][r0 * 32 + c0]);
        GLD_LDS16(&Ab[arow1 + kk], &As[slot][(r0 + 64) * 32 + c0]);
        GLD_LDS16(&Bb[brow0 + kk], &Bs[slot][r0 * 32 + c0]);
        GLD_LDS16(&Bb[brow1 + kk], &Bs[slot][(r0 + 64) * 32 + c0]);
      }
    }
  }
#pragma unroll
  for (int mi = 0; mi < 4; mi++)
#pragma unroll
    for (int ni = 0; ni < 4; ni++)
#pragma unroll
      for (int r = 0; r < 4; r++)
        Cw[(size_t)(m0 + wm + mi * 16 + quad * 4 + r) * N + n0 + wn + ni * 16 + l16] =
            acc[mi][ni][r];
}

// ---------------- bf16 GEMM, 64x128 tile, ring-4 (o-proj) ----------------
__global__ __launch_bounds__(256) void gemm_db_kernel(const short* __restrict__ A,
                                                      const short* __restrict__ B,
                                                      float* __restrict__ C, int N,
                                                      int gx, int gy, int P) {
  __shared__ __align__(16) short As[4][64 * 32];
  __shared__ __align__(16) short Bs[4][128 * 32];
  const int bid = blockIdx.x;
  const int xcd = bid & 7, idx = bid >> 3;
  const int colsPerX = gx >> 1, rowsPerX = gy >> 2;
  const int xt = (xcd & 1) * colsPerX + idx % colsPerX;
  const int yt = (xcd >> 1) * rowsPerX + idx / colsPerX;
  const int tid = threadIdx.x;
  const int lane = tid & 63, wave = tid >> 6;
  const int quad = lane >> 4, l16 = lane & 15;
  const int m0 = yt * 64, n0 = xt * 128;
  const int wm = (wave >> 1) * 32, wn = (wave & 1) * 64;
  const int r0 = tid >> 2, c0 = (tid & 3) * 8;
  const int ca = ((tid & 3) ^ ((r0 >> 1) & 3)) * 8;
  const size_t arow = (size_t)(m0 + r0) * 2048;
  const size_t brow0 = (size_t)(n0 + r0) * 2048, brow1 = (size_t)(n0 + r0 + 64) * 2048;
  f32x4 acc[2][4];
#pragma unroll
  for (int mi = 0; mi < 2; mi++)
#pragma unroll
    for (int ni = 0; ni < 4; ni++) acc[mi][ni] = (f32x4){0.f, 0.f, 0.f, 0.f};

#pragma unroll
  for (int st = 0; st < 4; st++) {
    const int kk = st * 32 + ca;
    GLD_LDS16(&A[arow + kk], &As[st][r0 * 32 + c0]);
    GLD_LDS16(&B[brow0 + kk], &Bs[st][r0 * 32 + c0]);
    GLD_LDS16(&B[brow1 + kk], &Bs[st][(r0 + 64) * 32 + c0]);
  }

  const int sx = (l16 >> 1) & 3;
  for (int p = 0; p < P; p++) {
    if (p < P - 1) {
      __asm__ volatile("s_waitcnt vmcnt(6)" ::: "memory");
    } else {
      __asm__ volatile("s_waitcnt vmcnt(0)" ::: "memory");
    }
    raw_barrier();
#pragma unroll
    for (int j = 0; j < 2; j++) {
      const int cur = (2 * p + j) & 3;
      bf16x8 af[2], bfr[4];
#pragma unroll
      for (int mi = 0; mi < 2; mi++)
        af[mi] = *(const bf16x8*)&As[cur][(wm + mi * 16 + l16) * 32 + ((quad ^ sx) * 8)];
#pragma unroll
      for (int ni = 0; ni < 4; ni++)
        bfr[ni] = *(const bf16x8*)&Bs[cur][(wn + ni * 16 + l16) * 32 + ((quad ^ sx) * 8)];
#pragma unroll
      for (int mi = 0; mi < 2; mi++)
#pragma unroll
        for (int ni = 0; ni < 4; ni++)
          acc[mi][ni] = MFMA16(af[mi], bfr[ni], acc[mi][ni]);
    }
    __asm__ volatile("s_waitcnt lgkmcnt(0)" ::: "memory");
    raw_barrier();
    if (p < P - 2) {
#pragma unroll
      for (int j = 0; j < 2; j++) {
        const int st = 2 * p + 4 + j;
        const int slot = st & 3;
        const int kk = st * 32 + ca;
        GLD_LDS16(&A[arow + kk], &As[slot][r0 * 32 + c0]);
        GLD_LDS16(&B[brow0 + kk], &Bs[slot][r0 * 32 + c0]);
        GLD_LDS16(&B[brow1 + kk], &Bs[slot][(r0 + 64) * 32 + c0]);
      }
    }
  }
#pragma unroll
  for (int mi = 0; mi < 2; mi++)
#pragma unroll
    for (int ni = 0; ni < 4; ni++)
#pragma unroll
      for (int r = 0; r < 4; r++)
        C[(size_t)(m0 + wm + mi * 16 + quad * 4 + r) * N + n0 + wn + ni * 16 + l16] =
            acc[mi][ni][r];
}

// ---------------- merged: Q/K post (bias+rmsnorm+rope+mask) AND V bias+mask+transpose ------
// Sums the two split-K partial buffers (qkv + qkv2) on every read.
__global__ __launch_bounds__(256) void postv_kernel(
    const float* __restrict__ qkv, const float* __restrict__ qkv2,
    const float* __restrict__ qbias, const float* __restrict__ kbias,
    const float* __restrict__ vbias, const float* __restrict__ qg,
    const float* __restrict__ kg, const float* __restrict__ cosb,
    const float* __restrict__ sinb, const float* __restrict__ maskp,
    short* __restrict__ qo, short* __restrict__ ko, short* __restrict__ vtb) {
  __shared__ short t[32][33];
  const int bid = blockIdx.x;
  if (bid < 9216) {
    const int rid = bid * 4 + (threadIdx.x >> 6);
    const int lane = threadIdx.x & 63;
    const int slot = rid >> 11;
    const int bs = rid & 2047;
    const int b = bs >> 10, s = bs & 1023;
    const float* row = qkv + (size_t)bs * 2560;
    const float* row2 = qkv2 + (size_t)bs * 2560;
    int off;
    const float* bias;
    const float* gamma;
    if (slot < 16) { off = slot * 128; bias = qbias + slot * 128; gamma = qg; }
    else { off = 2048 + (slot - 16) * 128; bias = kbias + (slot - 16) * 128; gamma = kg; }
    float v0 = row[off + lane] + row2[off + lane] + bias[lane];
    float v1 = row[off + 64 + lane] + row2[off + 64 + lane] + bias[64 + lane];
    float ss = v0 * v0 + v1 * v1;
#pragma unroll
    for (int o = 1; o < 64; o <<= 1) ss += __shfl_xor(ss, o);
    float r = rsqrtf(ss * (1.0f / 128.0f) + 1e-6f);
    v0 = gamma[lane] * v0 * r;
    v1 = gamma[64 + lane] * v1 * r;
    int sel = (lane < 16) ? 0 : (lane < 40) ? 1 : 2;
    size_t ci = ((size_t)(sel * 2 + b) * 1024 + s) * 128 + lane;
    float c0 = cosb[ci], s0 = sinb[ci], c1 = cosb[ci + 64], s1 = sinb[ci + 64];
    float o0 = v0 * c0 - v1 * s0;
    float o1 = v1 * c1 + v0 * s1;
    if (slot >= 16) { float mk = maskp[bs]; o0 *= mk; o1 *= mk; }
    size_t oidx;
    short* optr;
    if (slot < 16) { oidx = (((size_t)(b * 16 + slot) * 1024) + s) * 128; optr = qo; }
    else { oidx = (((size_t)(b * 2 + (slot - 16)) * 1024) + s) * 128; optr = ko; }
    optr[oidx + lane] = f2bf(o0);
    optr[oidx + 64 + lane] = f2bf(o1);
    return;
  }
  const int b2 = bid - 9216;
  const int d0 = (b2 & 3) * 32;
  const int s0 = ((b2 >> 2) & 31) * 32;
  const int bz = b2 >> 7;
  const int bq = bz >> 1, kv = bz & 1;
  const int tx = threadIdx.x & 31;
  const int ty = threadIdx.x >> 5;
#pragma unroll
  for (int i = 0; i < 4; i++) {
    int s = s0 + ty + i * 8;
    size_t qi = ((size_t)(bq * 1024 + s)) * 2560 + 2304 + kv * 128 + d0 + tx;
    float val = qkv[qi] + qkv2[qi] + vbias[kv * 128 + d0 + tx];
    t[ty + i * 8][tx] = f2bf(val * maskp[bq * 1024 + s]);
  }
  __syncthreads();
#pragma unroll
  for (int i = 0; i < 4; i++)
    vtb[((size_t)bz * 128 + d0 + ty + i * 8) * 1024 + s0 + tx] = t[tx][ty + i * 8];
}

// ---------------- flash attention, key-chunk split, FIXED-SHIFT softmax ----------------
// |score| <= sqrt(128) = 11.32 (rmsnorm'd q,k; rope preserves norm) -> exp(s-12) safe.
// Double-buffered ASYNC staging via global_load_lds; rule #21 swizzle. s_setprio(1)
// around MFMA clusters (T5: attn blocks are independent, +4-7% proven).
__global__ __launch_bounds__(256) void attn_kernel(const short* __restrict__ Q,
                                                   const short* __restrict__ K,
                                                   const short* __restrict__ Vt_g,
                                                   short* __restrict__ po,
                                                   float* __restrict__ pml) {
  int x = blockIdx.x;
  const int h = blockIdx.y;
  const int b = blockIdx.z;
  int g = 0, base = 0;
  while (x >= base + 4 * (g + 1)) { base += 4 * (g + 1); g++; }
  const int r0 = x - base;
  const int qt = 4 * g + r0 / (g + 1);
  const int kc = r0 % (g + 1);
  int nsteps = qt - 4 * kc + 1;
  if (nsteps > 4) nsteps = 4;

  const int kv = h >> 3;
  const int tid = threadIdx.x;
  const int wave = tid >> 6, lane = tid & 63;
  const int quad = lane >> 4, l16 = lane & 15;
  __shared__ __align__(16) short Ks[2][64 * 128];
  __shared__ __align__(16) short Vs[2][128 * 64];
  __shared__ __align__(16) short Ps[4][16 * 72];

  const size_t qoff = (((size_t)(b * 16 + h) * 1024) + qt * 64 + wave * 16 + l16) * 128;
  bf16x8 aq[4];
#pragma unroll
  for (int kk = 0; kk < 4; kk++) aq[kk] = *(const bf16x8*)&Q[qoff + kk * 32 + quad * 8];

  f32x4 o[8];
#pragma unroll
  for (int i = 0; i < 8; i++) o[i] = (f32x4){0.f, 0.f, 0.f, 0.f};
  float l[4] = {0.f, 0.f, 0.f, 0.f};
  const int qrow0 = qt * 64 + wave * 16 + quad * 4;
  const size_t koff = ((size_t)(b * 2 + kv) * 1024) * 128;
  const size_t voff = koff;
  const float scale = 0.08838834764831845f;  // 1/sqrt(128)

#define STAGE_KV(bf, ks0)                                                          \
  {                                                                                \
    _Pragma("unroll") for (int it = 0; it < 4; it++) {                             \
      const int c = it * 256 + tid;                                                \
      const int row = c >> 4, sl = c & 15;                                         \
      GLD_LDS16(&K[koff + (size_t)((ks0) + row) * 128 + ((sl ^ (row & 7)) * 8)],   \
                &Ks[bf][c * 8]);                                                   \
      const int d = c >> 3, sv = c & 7;                                            \
      GLD_LDS16(&Vt_g[voff + (size_t)d * 1024 + (ks0) + ((sv ^ (d & 7)) * 8)],     \
                &Vs[bf][c * 8]);                                                   \
    }                                                                              \
  }

  STAGE_KV(0, kc * 256);

  for (int st = 0; st < nsteps; st++) {
    __asm__ volatile("s_waitcnt vmcnt(0)" ::: "memory");
    raw_barrier();
    if (st + 1 < nsteps) { STAGE_KV((st + 1) & 1, kc * 256 + (st + 1) * 64); }
    const int cb = st & 1;
    const int ks0 = kc * 256 + st * 64;
    f32x4 sc[4];
#pragma unroll
    for (int nt = 0; nt < 4; nt++) sc[nt] = (f32x4){0.f, 0.f, 0.f, 0.f};
    __builtin_amdgcn_s_setprio(1);
#pragma unroll
    for (int nt = 0; nt < 4; nt++) {
      const int rr = nt * 16 + l16;
#pragma unroll
      for (int kk = 0; kk < 4; kk++) {
        bf16x8 bk = *(const bf16x8*)&Ks[cb][rr * 128 + (((kk * 4 + quad) ^ (rr & 7)) * 8)];
        sc[nt] = MFMA16(aq[kk], bk, sc[nt]);
      }
    }
    __builtin_amdgcn_s_setprio(0);
    // fixed-shift softmax weights: p = exp(s*scale - 12), causal-masked to 0
    short* P = &Ps[wave][0];
#pragma unroll
    for (int nt = 0; nt < 4; nt++) {
      const int kcol = ks0 + nt * 16 + l16;
#pragma unroll
      for (int r = 0; r < 4; r++) {
        float p = (kcol > qrow0 + r) ? 0.f : __expf(fmaf(sc[nt][r], scale, -12.0f));
        l[r] += p;
        P[(quad * 4 + r) * 72 + nt * 16 + l16] = f2bf(p);
      }
    }
    __asm__ volatile("s_waitcnt lgkmcnt(0)" ::: "memory");
    bf16x8 pa0 = *(const bf16x8*)&P[l16 * 72 + quad * 8];
    bf16x8 pa1 = *(const bf16x8*)&P[l16 * 72 + 32 + quad * 8];
    __builtin_amdgcn_s_setprio(1);
#pragma unroll
    for (int nt = 0; nt < 8; nt++) {
      const int rr = nt * 16 + l16;
      bf16x8 bv0 = *(const bf16x8*)&Vs[cb][rr * 64 + ((quad ^ (rr & 7)) * 8)];
      bf16x8 bv1 = *(const bf16x8*)&Vs[cb][rr * 64 + (((4 + quad) ^ (rr & 7)) * 8)];
      o[nt] = MFMA16(pa0, bv0, o[nt]);
      o[nt] = MFMA16(pa1, bv1, o[nt]);
    }
    __builtin_amdgcn_s_setprio(0);
  }
#undef STAGE_KV
#pragma unroll
  for (int off = 1; off < 16; off <<= 1)
#pragma unroll
    for (int r = 0; r < 4; r++) l[r] += __shfl_xor(l[r], off);
  const int p = (b * 16 + h) * 40 + blockIdx.x;
  const int lrow = wave * 16 + quad * 4;
#pragma unroll
  for (int nt = 0; nt < 8; nt++)
#pragma unroll
    for (int r = 0; r < 4; r++)
      po[(size_t)p * 8192 + (size_t)(lrow + r) * 128 + nt * 16 + l16] = f2bf(o[nt][r]);
  if (l16 == 0) {
#pragma unroll
    for (int r = 0; r < 4; r++) pml[(size_t)p * 64 + lrow + r] = l[r];
  }
}

// ---------------- combine partials (shared fixed shift -> plain sums) ----------------
__global__ __launch_bounds__(256) void attn_combine_kernel(const short* __restrict__ po,
                                                           const float* __restrict__ pml,
                                                           short* __restrict__ attn) {
  const int qt = blockIdx.x, h = blockIdx.y, b = blockIdx.z;
  const int g = qt >> 2, nc = g + 1;
  const int x0 = 2 * g * (g + 1) + (qt & 3) * nc;
  const int row = threadIdx.x >> 2;
  const int d0 = (threadIdx.x & 3) * 32;
  const int pbase = (b * 16 + h) * 40 + x0;
  float denom = 0.f;
#pragma unroll
  for (int kc = 0; kc < 4; kc++)
    if (kc < nc) denom += pml[(size_t)(pbase + kc) * 64 + row];
  float inv = 1.f / denom;
  float acc[32];
#pragma unroll
  for (int j = 0; j < 32; j++) acc[j] = 0.f;
#pragma unroll
  for (int kc = 0; kc < 4; kc++)
    if (kc < nc) {
      const short* src = po + (size_t)(pbase + kc) * 8192 + (size_t)row * 128 + d0;
#pragma unroll
      for (int j = 0; j < 4; j++) {
        int4 v = *(const int4*)&src[j * 8];
        const short* vs = (const short*)&v;
#pragma unroll
        for (int e = 0; e < 8; e++) acc[j * 8 + e] += bf2f(vs[e]);
      }
    }
  short ob[32];
#pragma unroll
  for (int j = 0; j < 32; j++) ob[j] = f2bf(acc[j] * inv);
  short* dst = attn + ((size_t)(b * 1024 + qt * 64 + row)) * 2048 + h * 128 + d0;
#pragma unroll
  for (int j = 0; j < 4; j++) *(int4*)&dst[j * 8] = *(const int4*)&ob[j * 8];
}

extern "C" void kernel_launch(void* const* d_in, const int* in_sizes, int n_in,
                              void* d_out, int out_size, void* d_ws, size_t ws_size,
                              hipStream_t stream) {
  const float* x = (const float*)d_in[0];
  const float* cosb = (const float*)d_in[1];
  const float* sinb = (const float*)d_in[2];
  const float* mask = (const float*)d_in[3];
  const float* q_w = (const float*)d_in[4];
  const float* q_b = (const float*)d_in[5];
  const float* k_w = (const float*)d_in[6];
  const float* k_b = (const float*)d_in[7];
  const float* v_w = (const float*)d_in[8];
  const float* v_b = (const float*)d_in[9];
  const float* qg = (const float*)d_in[10];
  const float* kg = (const float*)d_in[11];
  const float* o_w = (const float*)d_in[12];
  float* out = (float*)d_out;

  char* ws = (char*)d_ws;
  short* wo_t = (short*)(ws);
  short* wqkv_t = (short*)(ws + ((size_t)8 << 20));
  float* pml = (float*)(ws + ((size_t)8 << 20));
  short* attn = (short*)(ws + ((size_t)9 << 20));
  short* xb = (short*)(ws + ((size_t)18 << 20));
  short* qb = xb;
  float* qkv_raw = (float*)(ws + ((size_t)26 << 20));
  short* po = (short*)(ws + ((size_t)26 << 20));
  short* kb = (short*)(ws + ((size_t)46 << 20));
  short* vtb = (short*)(ws + ((size_t)47 << 20));
  float* qkv_raw2 = (float*)(ws + ((size_t)48 << 20));  // [48,68) MB: split-K partial

  prep_kernel<<<6400, 256, 0, stream>>>(x, q_w, k_w, v_w, o_w, xb, wqkv_t, wo_t);
  // QKV projection: 128x128 tile, split-K x2 (K=1024 each), 640 blocks (2 resident/CU)
  gemm128_kernel<<<640, 256, 0, stream>>>(xb, wqkv_t, qkv_raw, qkv_raw2, 2560, 20, 16, 16);
  postv_kernel<<<9728, 256, 0, stream>>>(qkv_raw, qkv_raw2, q_b, k_b, v_b, qg, kg, cosb,
                                         sinb, mask, qb, kb, vtb);
  attn_kernel<<<dim3(40, 16, 2), 256, 0, stream>>>(qb, kb, vtb, po, pml);
  attn_combine_kernel<<<dim3(16, 16, 2), 256, 0, stream>>>(po, pml, attn);
  // o-proj: 64x128 tile, single-K
  gemm_db_kernel<<<512, 256, 0, stream>>>(attn, wo_t, out, 2048, 16, 32, 32);
}

// Round 8
// 223.913 us; speedup vs baseline: 1.0250x; 1.0250x over previous
//
#include <hip/hip_runtime.h>

typedef __attribute__((ext_vector_type(8))) short bf16x8;
typedef __attribute__((ext_vector_type(4))) float f32x4;

#define MFMA16(a, b, c) __builtin_amdgcn_mfma_f32_16x16x32_bf16(a, b, c, 0, 0, 0)

__device__ inline short f2bf(float f) {
  union { float f; unsigned u; } v;
  v.f = f;
  unsigned r = v.u + 0x7FFF + ((v.u >> 16) & 1);
  return (short)(r >> 16);
}
__device__ inline float bf2f(short s) {
  union { unsigned u; float f; } v;
  v.u = ((unsigned)(unsigned short)s) << 16;
  return v.f;
}
#define GLD_LDS16(g, l)                                                        \
  __builtin_amdgcn_global_load_lds(                                            \
      (const __attribute__((address_space(1))) unsigned int*)(g),              \
      (__attribute__((address_space(3))) unsigned int*)(l), 16, 0, 0)

__device__ __forceinline__ void raw_barrier() {
  __asm__ volatile("" ::: "memory");
  __builtin_amdgcn_s_barrier();
  __asm__ volatile("" ::: "memory");
}

// ---------------- prep: x->bf16 + weight transposes + fused qkv bias vector ----------------
__global__ __launch_bounds__(256) void prep_kernel(
    const float* __restrict__ x, const float* __restrict__ q_w,
    const float* __restrict__ k_w, const float* __restrict__ v_w,
    const float* __restrict__ o_w, const float* __restrict__ q_b,
    const float* __restrict__ k_b, const float* __restrict__ v_b,
    short* __restrict__ xb, short* __restrict__ wqkv_t, short* __restrict__ wo_t,
    float* __restrict__ biasAll) {
  __shared__ float t[64][65];
  int bid = blockIdx.x;
  if (bid == 6400) {  // fused bias vector [q_b | k_b | v_b]
    for (int i = threadIdx.x; i < 2560; i += 256) {
      float v = (i < 2048) ? q_b[i] : (i < 2304 ? k_b[i - 2048] : v_b[i - 2304]);
      biasAll[i] = v;
    }
    return;
  }
  if (bid < 4096) {  // cvt x
    int i = (bid * 256 + threadIdx.x) * 4;
    float4 f = *(const float4*)&x[i];
    short4 o;
    o.x = f2bf(f.x); o.y = f2bf(f.y); o.z = f2bf(f.z); o.w = f2bf(f.w);
    *(short4*)&xb[i] = o;
    return;
  }
  bid -= 4096;
  const float* src;
  short* dst;
  int C, bx, by;
  if (bid < 1024) {
    src = q_w; dst = wqkv_t; C = 2048;
    bx = (bid & 31) * 64; by = (bid >> 5) * 64;
  } else if (bid < 1152) {
    bid -= 1024;
    src = k_w; dst = wqkv_t + (size_t)2048 * 2048; C = 256;
    bx = (bid & 3) * 64; by = (bid >> 2) * 64;
  } else if (bid < 1280) {
    bid -= 1152;
    src = v_w; dst = wqkv_t + (size_t)2304 * 2048; C = 256;
    bx = (bid & 3) * 64; by = (bid >> 2) * 64;
  } else {
    bid -= 1280;
    src = o_w; dst = wo_t; C = 2048;
    bx = (bid & 31) * 64; by = (bid >> 5) * 64;
  }
  const int R = 2048;
  const int tx = threadIdx.x & 15;
  const int ty = threadIdx.x >> 4;
#pragma unroll
  for (int i = 0; i < 4; i++) {
    int row = ty + i * 16;
    float4 f = *(const float4*)&src[(size_t)(by + row) * C + bx + tx * 4];
    t[row][tx * 4 + 0] = f.x;
    t[row][tx * 4 + 1] = f.y;
    t[row][tx * 4 + 2] = f.z;
    t[row][tx * 4 + 3] = f.w;
  }
  __syncthreads();
#pragma unroll
  for (int i = 0; i < 4; i++) {
    int c = ty + i * 16;
    short4 o;
    o.x = f2bf(t[tx * 4 + 0][c]);
    o.y = f2bf(t[tx * 4 + 1][c]);
    o.z = f2bf(t[tx * 4 + 2][c]);
    o.w = f2bf(t[tx * 4 + 3][c]);
    *(short4*)&dst[(size_t)(bx + c) * R + by + tx * 4] = o;
  }
}

// ---------------- QKV GEMM: 64x128 tile, ring-4, bias + bf16 epilogue ----------------
// Single-K (640 blocks, ~2.5/CU at 48KB LDS). Conflict-free swizzle (R6-verified:
// SQ_LDS_BANK_CONFLICT = 0): source col pre-XOR ((r>>1)&3), read XOR (l16>>1)&3.
// Epilogue adds bias in f32 then writes bf16 -> kills the 21MB f32 round-trip to postv.
__global__ __launch_bounds__(256) void gemm_qkv_kernel(const short* __restrict__ A,
                                                       const short* __restrict__ B,
                                                       short* __restrict__ Cs,
                                                       const float* __restrict__ bias,
                                                       int N, int gx, int gy, int P) {
  __shared__ __align__(16) short As[4][64 * 32];
  __shared__ __align__(16) short Bs[4][128 * 32];
  const int bid = blockIdx.x;
  const int xcd = bid & 7, idx = bid >> 3;
  const int colsPerX = gx >> 1, rowsPerX = gy >> 2;
  const int xt = (xcd & 1) * colsPerX + idx % colsPerX;
  const int yt = (xcd >> 1) * rowsPerX + idx / colsPerX;
  const int tid = threadIdx.x;
  const int lane = tid & 63, wave = tid >> 6;
  const int quad = lane >> 4, l16 = lane & 15;
  const int m0 = yt * 64, n0 = xt * 128;
  const int wm = (wave >> 1) * 32, wn = (wave & 1) * 64;
  const int r0 = tid >> 2, c0 = (tid & 3) * 8;
  const int ca = ((tid & 3) ^ ((r0 >> 1) & 3)) * 8;
  const size_t arow = (size_t)(m0 + r0) * 2048;
  const size_t brow0 = (size_t)(n0 + r0) * 2048, brow1 = (size_t)(n0 + r0 + 64) * 2048;
  f32x4 acc[2][4];
#pragma unroll
  for (int mi = 0; mi < 2; mi++)
#pragma unroll
    for (int ni = 0; ni < 4; ni++) acc[mi][ni] = (f32x4){0.f, 0.f, 0.f, 0.f};

#pragma unroll
  for (int st = 0; st < 4; st++) {
    const int kk = st * 32 + ca;
    GLD_LDS16(&A[arow + kk], &As[st][r0 * 32 + c0]);
    GLD_LDS16(&B[brow0 + kk], &Bs[st][r0 * 32 + c0]);
    GLD_LDS16(&B[brow1 + kk], &Bs[st][(r0 + 64) * 32 + c0]);
  }

  const int sx = (l16 >> 1) & 3;
  for (int p = 0; p < P; p++) {
    if (p < P - 1) {
      __asm__ volatile("s_waitcnt vmcnt(6)" ::: "memory");
    } else {
      __asm__ volatile("s_waitcnt vmcnt(0)" ::: "memory");
    }
    raw_barrier();
#pragma unroll
    for (int j = 0; j < 2; j++) {
      const int cur = (2 * p + j) & 3;
      bf16x8 af[2], bfr[4];
#pragma unroll
      for (int mi = 0; mi < 2; mi++)
        af[mi] = *(const bf16x8*)&As[cur][(wm + mi * 16 + l16) * 32 + ((quad ^ sx) * 8)];
#pragma unroll
      for (int ni = 0; ni < 4; ni++)
        bfr[ni] = *(const bf16x8*)&Bs[cur][(wn + ni * 16 + l16) * 32 + ((quad ^ sx) * 8)];
#pragma unroll
      for (int mi = 0; mi < 2; mi++)
#pragma unroll
        for (int ni = 0; ni < 4; ni++)
          acc[mi][ni] = MFMA16(af[mi], bfr[ni], acc[mi][ni]);
    }
    __asm__ volatile("s_waitcnt lgkmcnt(0)" ::: "memory");
    raw_barrier();
    if (p < P - 2) {
#pragma unroll
      for (int j = 0; j < 2; j++) {
        const int st = 2 * p + 4 + j;
        const int slot = st & 3;
        const int kk = st * 32 + ca;
        GLD_LDS16(&A[arow + kk], &As[slot][r0 * 32 + c0]);
        GLD_LDS16(&B[brow0 + kk], &Bs[slot][r0 * 32 + c0]);
        GLD_LDS16(&B[brow1 + kk], &Bs[slot][(r0 + 64) * 32 + c0]);
      }
    }
  }
#pragma unroll
  for (int mi = 0; mi < 2; mi++)
#pragma unroll
    for (int ni = 0; ni < 4; ni++) {
      const int col = n0 + wn + ni * 16 + l16;
      const float bv = bias[col];
#pragma unroll
      for (int r = 0; r < 4; r++)
        Cs[(size_t)(m0 + wm + mi * 16 + quad * 4 + r) * N + col] =
            f2bf(acc[mi][ni][r] + bv);
    }
}

// ---------------- bf16 GEMM, 64x128 tile, ring-4, f32 out (o-proj) ----------------
__global__ __launch_bounds__(256) void gemm_db_kernel(const short* __restrict__ A,
                                                      const short* __restrict__ B,
                                                      float* __restrict__ C, int N,
                                                      int gx, int gy, int P) {
  __shared__ __align__(16) short As[4][64 * 32];
  __shared__ __align__(16) short Bs[4][128 * 32];
  const int bid = blockIdx.x;
  const int xcd = bid & 7, idx = bid >> 3;
  const int colsPerX = gx >> 1, rowsPerX = gy >> 2;
  const int xt = (xcd & 1) * colsPerX + idx % colsPerX;
  const int yt = (xcd >> 1) * rowsPerX + idx / colsPerX;
  const int tid = threadIdx.x;
  const int lane = tid & 63, wave = tid >> 6;
  const int quad = lane >> 4, l16 = lane & 15;
  const int m0 = yt * 64, n0 = xt * 128;
  const int wm = (wave >> 1) * 32, wn = (wave & 1) * 64;
  const int r0 = tid >> 2, c0 = (tid & 3) * 8;
  const int ca = ((tid & 3) ^ ((r0 >> 1) & 3)) * 8;
  const size_t arow = (size_t)(m0 + r0) * 2048;
  const size_t brow0 = (size_t)(n0 + r0) * 2048, brow1 = (size_t)(n0 + r0 + 64) * 2048;
  f32x4 acc[2][4];
#pragma unroll
  for (int mi = 0; mi < 2; mi++)
#pragma unroll
    for (int ni = 0; ni < 4; ni++) acc[mi][ni] = (f32x4){0.f, 0.f, 0.f, 0.f};

#pragma unroll
  for (int st = 0; st < 4; st++) {
    const int kk = st * 32 + ca;
    GLD_LDS16(&A[arow + kk], &As[st][r0 * 32 + c0]);
    GLD_LDS16(&B[brow0 + kk], &Bs[st][r0 * 32 + c0]);
    GLD_LDS16(&B[brow1 + kk], &Bs[st][(r0 + 64) * 32 + c0]);
  }

  const int sx = (l16 >> 1) & 3;
  for (int p = 0; p < P; p++) {
    if (p < P - 1) {
      __asm__ volatile("s_waitcnt vmcnt(6)" ::: "memory");
    } else {
      __asm__ volatile("s_waitcnt vmcnt(0)" ::: "memory");
    }
    raw_barrier();
#pragma unroll
    for (int j = 0; j < 2; j++) {
      const int cur = (2 * p + j) & 3;
      bf16x8 af[2], bfr[4];
#pragma unroll
      for (int mi = 0; mi < 2; mi++)
        af[mi] = *(const bf16x8*)&As[cur][(wm + mi * 16 + l16) * 32 + ((quad ^ sx) * 8)];
#pragma unroll
      for (int ni = 0; ni < 4; ni++)
        bfr[ni] = *(const bf16x8*)&Bs[cur][(wn + ni * 16 + l16) * 32 + ((quad ^ sx) * 8)];
#pragma unroll
      for (int mi = 0; mi < 2; mi++)
#pragma unroll
        for (int ni = 0; ni < 4; ni++)
          acc[mi][ni] = MFMA16(af[mi], bfr[ni], acc[mi][ni]);
    }
    __asm__ volatile("s_waitcnt lgkmcnt(0)" ::: "memory");
    raw_barrier();
    if (p < P - 2) {
#pragma unroll
      for (int j = 0; j < 2; j++) {
        const int st = 2 * p + 4 + j;
        const int slot = st & 3;
        const int kk = st * 32 + ca;
        GLD_LDS16(&A[arow + kk], &As[slot][r0 * 32 + c0]);
        GLD_LDS16(&B[brow0 + kk], &Bs[slot][r0 * 32 + c0]);
        GLD_LDS16(&B[brow1 + kk], &Bs[slot][(r0 + 64) * 32 + c0]);
      }
    }
  }
#pragma unroll
  for (int mi = 0; mi < 2; mi++)
#pragma unroll
    for (int ni = 0; ni < 4; ni++)
#pragma unroll
      for (int r = 0; r < 4; r++)
        C[(size_t)(m0 + wm + mi * 16 + quad * 4 + r) * N + n0 + wn + ni * 16 + l16] =
            acc[mi][ni][r];
}

// ---------------- merged: Q/K post (rmsnorm+rope+mask) AND V mask+transpose ------
// Reads the bf16 qkv buffer (bias already applied in the GEMM epilogue).
__global__ __launch_bounds__(256) void postv_kernel(
    const short* __restrict__ qkvb, const float* __restrict__ qg,
    const float* __restrict__ kg, const float* __restrict__ cosb,
    const float* __restrict__ sinb, const float* __restrict__ maskp,
    short* __restrict__ qo, short* __restrict__ ko, short* __restrict__ vtb) {
  __shared__ short t[32][33];
  const int bid = blockIdx.x;
  if (bid < 9216) {
    const int rid = bid * 4 + (threadIdx.x >> 6);
    const int lane = threadIdx.x & 63;
    const int slot = rid >> 11;
    const int bs = rid & 2047;
    const int b = bs >> 10, s = bs & 1023;
    const short* row = qkvb + (size_t)bs * 2560;
    int off;
    const float* gamma;
    if (slot < 16) { off = slot * 128; gamma = qg; }
    else { off = 2048 + (slot - 16) * 128; gamma = kg; }
    float v0 = bf2f(row[off + lane]);
    float v1 = bf2f(row[off + 64 + lane]);
    float ss = v0 * v0 + v1 * v1;
#pragma unroll
    for (int o = 1; o < 64; o <<= 1) ss += __shfl_xor(ss, o);
    float r = rsqrtf(ss * (1.0f / 128.0f) + 1e-6f);
    v0 = gamma[lane] * v0 * r;
    v1 = gamma[64 + lane] * v1 * r;
    int sel = (lane < 16) ? 0 : (lane < 40) ? 1 : 2;
    size_t ci = ((size_t)(sel * 2 + b) * 1024 + s) * 128 + lane;
    float c0 = cosb[ci], s0 = sinb[ci], c1 = cosb[ci + 64], s1 = sinb[ci + 64];
    float o0 = v0 * c0 - v1 * s0;
    float o1 = v1 * c1 + v0 * s1;
    if (slot >= 16) { float mk = maskp[bs]; o0 *= mk; o1 *= mk; }
    size_t oidx;
    short* optr;
    if (slot < 16) { oidx = (((size_t)(b * 16 + slot) * 1024) + s) * 128; optr = qo; }
    else { oidx = (((size_t)(b * 2 + (slot - 16)) * 1024) + s) * 128; optr = ko; }
    optr[oidx + lane] = f2bf(o0);
    optr[oidx + 64 + lane] = f2bf(o1);
    return;
  }
  const int b2 = bid - 9216;
  const int d0 = (b2 & 3) * 32;
  const int s0 = ((b2 >> 2) & 31) * 32;
  const int bz = b2 >> 7;
  const int bq = bz >> 1, kv = bz & 1;
  const int tx = threadIdx.x & 31;
  const int ty = threadIdx.x >> 5;
#pragma unroll
  for (int i = 0; i < 4; i++) {
    int s = s0 + ty + i * 8;
    size_t qi = ((size_t)(bq * 1024 + s)) * 2560 + 2304 + kv * 128 + d0 + tx;
    float val = bf2f(qkvb[qi]);
    t[ty + i * 8][tx] = f2bf(val * maskp[bq * 1024 + s]);
  }
  __syncthreads();
#pragma unroll
  for (int i = 0; i < 4; i++)
    vtb[((size_t)bz * 128 + d0 + ty + i * 8) * 1024 + s0 + tx] = t[tx][ty + i * 8];
}

// ---------------- flash attention, key-chunk split, FIXED-SHIFT softmax ----------------
// |score| <= sqrt(128) = 11.32 (rmsnorm'd q,k; rope preserves norm) -> exp(s-12) safe.
// Double-buffered ASYNC staging via global_load_lds; rule #21 swizzle; T5 setprio.
__global__ __launch_bounds__(256) void attn_kernel(const short* __restrict__ Q,
                                                   const short* __restrict__ K,
                                                   const short* __restrict__ Vt_g,
                                                   short* __restrict__ po,
                                                   float* __restrict__ pml) {
  int x = blockIdx.x;
  const int h = blockIdx.y;
  const int b = blockIdx.z;
  int g = 0, base = 0;
  while (x >= base + 4 * (g + 1)) { base += 4 * (g + 1); g++; }
  const int r0 = x - base;
  const int qt = 4 * g + r0 / (g + 1);
  const int kc = r0 % (g + 1);
  int nsteps = qt - 4 * kc + 1;
  if (nsteps > 4) nsteps = 4;

  const int kv = h >> 3;
  const int tid = threadIdx.x;
  const int wave = tid >> 6, lane = tid & 63;
  const int quad = lane >> 4, l16 = lane & 15;
  __shared__ __align__(16) short Ks[2][64 * 128];
  __shared__ __align__(16) short Vs[2][128 * 64];
  __shared__ __align__(16) short Ps[4][16 * 72];

  const size_t qoff = (((size_t)(b * 16 + h) * 1024) + qt * 64 + wave * 16 + l16) * 128;
  bf16x8 aq[4];
#pragma unroll
  for (int kk = 0; kk < 4; kk++) aq[kk] = *(const bf16x8*)&Q[qoff + kk * 32 + quad * 8];

  f32x4 o[8];
#pragma unroll
  for (int i = 0; i < 8; i++) o[i] = (f32x4){0.f, 0.f, 0.f, 0.f};
  float l[4] = {0.f, 0.f, 0.f, 0.f};
  const int qrow0 = qt * 64 + wave * 16 + quad * 4;
  const size_t koff = ((size_t)(b * 2 + kv) * 1024) * 128;
  const size_t voff = koff;
  const float scale = 0.08838834764831845f;  // 1/sqrt(128)

#define STAGE_KV(bf, ks0)                                                          \
  {                                                                                \
    _Pragma("unroll") for (int it = 0; it < 4; it++) {                             \
      const int c = it * 256 + tid;                                                \
      const int row = c >> 4, sl = c & 15;                                         \
      GLD_LDS16(&K[koff + (size_t)((ks0) + row) * 128 + ((sl ^ (row & 7)) * 8)],   \
                &Ks[bf][c * 8]);                                                   \
      const int d = c >> 3, sv = c & 7;                                            \
      GLD_LDS16(&Vt_g[voff + (size_t)d * 1024 + (ks0) + ((sv ^ (d & 7)) * 8)],     \
                &Vs[bf][c * 8]);                                                   \
    }                                                                              \
  }

  STAGE_KV(0, kc * 256);

  for (int st = 0; st < nsteps; st++) {
    __asm__ volatile("s_waitcnt vmcnt(0)" ::: "memory");
    raw_barrier();
    if (st + 1 < nsteps) { STAGE_KV((st + 1) & 1, kc * 256 + (st + 1) * 64); }
    const int cb = st & 1;
    const int ks0 = kc * 256 + st * 64;
    f32x4 sc[4];
#pragma unroll
    for (int nt = 0; nt < 4; nt++) sc[nt] = (f32x4){0.f, 0.f, 0.f, 0.f};
    __builtin_amdgcn_s_setprio(1);
#pragma unroll
    for (int nt = 0; nt < 4; nt++) {
      const int rr = nt * 16 + l16;
#pragma unroll
      for (int kk = 0; kk < 4; kk++) {
        bf16x8 bk = *(const bf16x8*)&Ks[cb][rr * 128 + (((kk * 4 + quad) ^ (rr & 7)) * 8)];
        sc[nt] = MFMA16(aq[kk], bk, sc[nt]);
      }
    }
    __builtin_amdgcn_s_setprio(0);
    // fixed-shift softmax weights: p = exp(s*scale - 12), causal-masked to 0
    short* P = &Ps[wave][0];
#pragma unroll
    for (int nt = 0; nt < 4; nt++) {
      const int kcol = ks0 + nt * 16 + l16;
#pragma unroll
      for (int r = 0; r < 4; r++) {
        float p = (kcol > qrow0 + r) ? 0.f : __expf(fmaf(sc[nt][r], scale, -12.0f));
        l[r] += p;
        P[(quad * 4 + r) * 72 + nt * 16 + l16] = f2bf(p);
      }
    }
    __asm__ volatile("s_waitcnt lgkmcnt(0)" ::: "memory");
    bf16x8 pa0 = *(const bf16x8*)&P[l16 * 72 + quad * 8];
    bf16x8 pa1 = *(const bf16x8*)&P[l16 * 72 + 32 + quad * 8];
    __builtin_amdgcn_s_setprio(1);
#pragma unroll
    for (int nt = 0; nt < 8; nt++) {
      const int rr = nt * 16 + l16;
      bf16x8 bv0 = *(const bf16x8*)&Vs[cb][rr * 64 + ((quad ^ (rr & 7)) * 8)];
      bf16x8 bv1 = *(const bf16x8*)&Vs[cb][rr * 64 + (((4 + quad) ^ (rr & 7)) * 8)];
      o[nt] = MFMA16(pa0, bv0, o[nt]);
      o[nt] = MFMA16(pa1, bv1, o[nt]);
    }
    __builtin_amdgcn_s_setprio(0);
  }
#undef STAGE_KV
#pragma unroll
  for (int off = 1; off < 16; off <<= 1)
#pragma unroll
    for (int r = 0; r < 4; r++) l[r] += __shfl_xor(l[r], off);
  const int p = (b * 16 + h) * 40 + blockIdx.x;
  const int lrow = wave * 16 + quad * 4;
#pragma unroll
  for (int nt = 0; nt < 8; nt++)
#pragma unroll
    for (int r = 0; r < 4; r++)
      po[(size_t)p * 8192 + (size_t)(lrow + r) * 128 + nt * 16 + l16] = f2bf(o[nt][r]);
  if (l16 == 0) {
#pragma unroll
    for (int r = 0; r < 4; r++) pml[(size_t)p * 64 + lrow + r] = l[r];
  }
}

// ---------------- combine partials (shared fixed shift -> plain sums) ----------------
__global__ __launch_bounds__(256) void attn_combine_kernel(const short* __restrict__ po,
                                                           const float* __restrict__ pml,
                                                           short* __restrict__ attn) {
  const int qt = blockIdx.x, h = blockIdx.y, b = blockIdx.z;
  const int g = qt >> 2, nc = g + 1;
  const int x0 = 2 * g * (g + 1) + (qt & 3) * nc;
  const int row = threadIdx.x >> 2;
  const int d0 = (threadIdx.x & 3) * 32;
  const int pbase = (b * 16 + h) * 40 + x0;
  float denom = 0.f;
#pragma unroll
  for (int kc = 0; kc < 4; kc++)
    if (kc < nc) denom += pml[(size_t)(pbase + kc) * 64 + row];
  float inv = 1.f / denom;
  float acc[32];
#pragma unroll
  for (int j = 0; j < 32; j++) acc[j] = 0.f;
#pragma unroll
  for (int kc = 0; kc < 4; kc++)
    if (kc < nc) {
      const short* src = po + (size_t)(pbase + kc) * 8192 + (size_t)row * 128 + d0;
#pragma unroll
      for (int j = 0; j < 4; j++) {
        int4 v = *(const int4*)&src[j * 8];
        const short* vs = (const short*)&v;
#pragma unroll
        for (int e = 0; e < 8; e++) acc[j * 8 + e] += bf2f(vs[e]);
      }
    }
  short ob[32];
#pragma unroll
  for (int j = 0; j < 32; j++) ob[j] = f2bf(acc[j] * inv);
  short* dst = attn + ((size_t)(b * 1024 + qt * 64 + row)) * 2048 + h * 128 + d0;
#pragma unroll
  for (int j = 0; j < 4; j++) *(int4*)&dst[j * 8] = *(const int4*)&ob[j * 8];
}

extern "C" void kernel_launch(void* const* d_in, const int* in_sizes, int n_in,
                              void* d_out, int out_size, void* d_ws, size_t ws_size,
                              hipStream_t stream) {
  const float* x = (const float*)d_in[0];
  const float* cosb = (const float*)d_in[1];
  const float* sinb = (const float*)d_in[2];
  const float* mask = (const float*)d_in[3];
  const float* q_w = (const float*)d_in[4];
  const float* q_b = (const float*)d_in[5];
  const float* k_w = (const float*)d_in[6];
  const float* k_b = (const float*)d_in[7];
  const float* v_w = (const float*)d_in[8];
  const float* v_b = (const float*)d_in[9];
  const float* qg = (const float*)d_in[10];
  const float* kg = (const float*)d_in[11];
  const float* o_w = (const float*)d_in[12];
  float* out = (float*)d_out;

  char* ws = (char*)d_ws;
  short* wo_t = (short*)(ws);                              // [0,8) MB
  short* wqkv_t = (short*)(ws + ((size_t)8 << 20));        // [8,18) MB (dead after gemm)
  float* pml = (float*)(ws + ((size_t)8 << 20));           // aliases wqkv_t (after)
  short* attn = (short*)(ws + ((size_t)9 << 20));          // aliases wqkv_t (after)
  short* xb = (short*)(ws + ((size_t)18 << 20));           // [18,26.4) MB
  short* qb = xb;
  short* po = (short*)(ws + ((size_t)26 << 20));           // [26,46) MB
  short* kb = (short*)(ws + ((size_t)46 << 20));           // [46,47)
  short* vtb = (short*)(ws + ((size_t)47 << 20));          // [47,48)
  short* qkvb = (short*)(ws + ((size_t)48 << 20));         // [48,58) MB bf16 qkv
  float* biasAll = (float*)(ws + ((size_t)68 << 20));      // 10 KB fused bias

  prep_kernel<<<6401, 256, 0, stream>>>(x, q_w, k_w, v_w, o_w, q_b, k_b, v_b, xb,
                                        wqkv_t, wo_t, biasAll);
  gemm_qkv_kernel<<<640, 256, 0, stream>>>(xb, wqkv_t, qkvb, biasAll, 2560, 20, 32, 32);
  postv_kernel<<<9728, 256, 0, stream>>>(qkvb, qg, kg, cosb, sinb, mask, qb, kb, vtb);
  attn_kernel<<<dim3(40, 16, 2), 256, 0, stream>>>(qb, kb, vtb, po, pml);
  attn_combine_kernel<<<dim3(16, 16, 2), 256, 0, stream>>>(po, pml, attn);
  gemm_db_kernel<<<512, 256, 0, stream>>>(attn, wo_t, out, 2048, 16, 32, 32);
}

// Round 9
// 222.331 us; speedup vs baseline: 1.0323x; 1.0071x over previous
//
#include <hip/hip_runtime.h>

typedef __attribute__((ext_vector_type(8))) short bf16x8;
typedef __attribute__((ext_vector_type(4))) float f32x4;

#define MFMA16(a, b, c) __builtin_amdgcn_mfma_f32_16x16x32_bf16(a, b, c, 0, 0, 0)

__device__ inline short f2bf(float f) {
  union { float f; unsigned u; } v;
  v.f = f;
  unsigned r = v.u + 0x7FFF + ((v.u >> 16) & 1);
  return (short)(r >> 16);
}
__device__ inline float bf2f(short s) {
  union { unsigned u; float f; } v;
  v.u = ((unsigned)(unsigned short)s) << 16;
  return v.f;
}
#define GLD_LDS16(g, l)                                                        \
  __builtin_amdgcn_global_load_lds(                                            \
      (const __attribute__((address_space(1))) unsigned int*)(g),              \
      (__attribute__((address_space(3))) unsigned int*)(l), 16, 0, 0)

__device__ __forceinline__ void raw_barrier() {
  __asm__ volatile("" ::: "memory");
  __builtin_amdgcn_s_barrier();
  __asm__ volatile("" ::: "memory");
}

// ---------------- prep: x->bf16 + weight transposes + fused qkv bias vector ----------------
__global__ __launch_bounds__(256) void prep_kernel(
    const float* __restrict__ x, const float* __restrict__ q_w,
    const float* __restrict__ k_w, const float* __restrict__ v_w,
    const float* __restrict__ o_w, const float* __restrict__ q_b,
    const float* __restrict__ k_b, const float* __restrict__ v_b,
    short* __restrict__ xb, short* __restrict__ wqkv_t, short* __restrict__ wo_t,
    float* __restrict__ biasAll) {
  __shared__ float t[64][65];
  int bid = blockIdx.x;
  if (bid == 6400) {  // fused bias vector [q_b | k_b | v_b]
    for (int i = threadIdx.x; i < 2560; i += 256) {
      float v = (i < 2048) ? q_b[i] : (i < 2304 ? k_b[i - 2048] : v_b[i - 2304]);
      biasAll[i] = v;
    }
    return;
  }
  if (bid < 4096) {  // cvt x
    int i = (bid * 256 + threadIdx.x) * 4;
    float4 f = *(const float4*)&x[i];
    short4 o;
    o.x = f2bf(f.x); o.y = f2bf(f.y); o.z = f2bf(f.z); o.w = f2bf(f.w);
    *(short4*)&xb[i] = o;
    return;
  }
  bid -= 4096;
  const float* src;
  short* dst;
  int C, bx, by;
  if (bid < 1024) {
    src = q_w; dst = wqkv_t; C = 2048;
    bx = (bid & 31) * 64; by = (bid >> 5) * 64;
  } else if (bid < 1152) {
    bid -= 1024;
    src = k_w; dst = wqkv_t + (size_t)2048 * 2048; C = 256;
    bx = (bid & 3) * 64; by = (bid >> 2) * 64;
  } else if (bid < 1280) {
    bid -= 1152;
    src = v_w; dst = wqkv_t + (size_t)2304 * 2048; C = 256;
    bx = (bid & 3) * 64; by = (bid >> 2) * 64;
  } else {
    bid -= 1280;
    src = o_w; dst = wo_t; C = 2048;
    bx = (bid & 31) * 64; by = (bid >> 5) * 64;
  }
  const int R = 2048;
  const int tx = threadIdx.x & 15;
  const int ty = threadIdx.x >> 4;
#pragma unroll
  for (int i = 0; i < 4; i++) {
    int row = ty + i * 16;
    float4 f = *(const float4*)&src[(size_t)(by + row) * C + bx + tx * 4];
    t[row][tx * 4 + 0] = f.x;
    t[row][tx * 4 + 1] = f.y;
    t[row][tx * 4 + 2] = f.z;
    t[row][tx * 4 + 3] = f.w;
  }
  __syncthreads();
#pragma unroll
  for (int i = 0; i < 4; i++) {
    int c = ty + i * 16;
    short4 o;
    o.x = f2bf(t[tx * 4 + 0][c]);
    o.y = f2bf(t[tx * 4 + 1][c]);
    o.z = f2bf(t[tx * 4 + 2][c]);
    o.w = f2bf(t[tx * 4 + 3][c]);
    *(short4*)&dst[(size_t)(bx + c) * R + by + tx * 4] = o;
  }
}

// ---------------- QKV GEMM: 64x128 tile, ring-4, bias + bf16 epilogue ----------------
__global__ __launch_bounds__(256) void gemm_qkv_kernel(const short* __restrict__ A,
                                                       const short* __restrict__ B,
                                                       short* __restrict__ Cs,
                                                       const float* __restrict__ bias,
                                                       int N, int gx, int gy, int P) {
  __shared__ __align__(16) short As[4][64 * 32];
  __shared__ __align__(16) short Bs[4][128 * 32];
  const int bid = blockIdx.x;
  const int xcd = bid & 7, idx = bid >> 3;
  const int colsPerX = gx >> 1, rowsPerX = gy >> 2;
  const int xt = (xcd & 1) * colsPerX + idx % colsPerX;
  const int yt = (xcd >> 1) * rowsPerX + idx / colsPerX;
  const int tid = threadIdx.x;
  const int lane = tid & 63, wave = tid >> 6;
  const int quad = lane >> 4, l16 = lane & 15;
  const int m0 = yt * 64, n0 = xt * 128;
  const int wm = (wave >> 1) * 32, wn = (wave & 1) * 64;
  const int r0 = tid >> 2, c0 = (tid & 3) * 8;
  const int ca = ((tid & 3) ^ ((r0 >> 1) & 3)) * 8;
  const size_t arow = (size_t)(m0 + r0) * 2048;
  const size_t brow0 = (size_t)(n0 + r0) * 2048, brow1 = (size_t)(n0 + r0 + 64) * 2048;
  f32x4 acc[2][4];
#pragma unroll
  for (int mi = 0; mi < 2; mi++)
#pragma unroll
    for (int ni = 0; ni < 4; ni++) acc[mi][ni] = (f32x4){0.f, 0.f, 0.f, 0.f};

#pragma unroll
  for (int st = 0; st < 4; st++) {
    const int kk = st * 32 + ca;
    GLD_LDS16(&A[arow + kk], &As[st][r0 * 32 + c0]);
    GLD_LDS16(&B[brow0 + kk], &Bs[st][r0 * 32 + c0]);
    GLD_LDS16(&B[brow1 + kk], &Bs[st][(r0 + 64) * 32 + c0]);
  }

  const int sx = (l16 >> 1) & 3;
  for (int p = 0; p < P; p++) {
    if (p < P - 1) {
      __asm__ volatile("s_waitcnt vmcnt(6)" ::: "memory");
    } else {
      __asm__ volatile("s_waitcnt vmcnt(0)" ::: "memory");
    }
    raw_barrier();
#pragma unroll
    for (int j = 0; j < 2; j++) {
      const int cur = (2 * p + j) & 3;
      bf16x8 af[2], bfr[4];
#pragma unroll
      for (int mi = 0; mi < 2; mi++)
        af[mi] = *(const bf16x8*)&As[cur][(wm + mi * 16 + l16) * 32 + ((quad ^ sx) * 8)];
#pragma unroll
      for (int ni = 0; ni < 4; ni++)
        bfr[ni] = *(const bf16x8*)&Bs[cur][(wn + ni * 16 + l16) * 32 + ((quad ^ sx) * 8)];
#pragma unroll
      for (int mi = 0; mi < 2; mi++)
#pragma unroll
        for (int ni = 0; ni < 4; ni++)
          acc[mi][ni] = MFMA16(af[mi], bfr[ni], acc[mi][ni]);
    }
    __asm__ volatile("s_waitcnt lgkmcnt(0)" ::: "memory");
    raw_barrier();
    if (p < P - 2) {
#pragma unroll
      for (int j = 0; j < 2; j++) {
        const int st = 2 * p + 4 + j;
        const int slot = st & 3;
        const int kk = st * 32 + ca;
        GLD_LDS16(&A[arow + kk], &As[slot][r0 * 32 + c0]);
        GLD_LDS16(&B[brow0 + kk], &Bs[slot][r0 * 32 + c0]);
        GLD_LDS16(&B[brow1 + kk], &Bs[slot][(r0 + 64) * 32 + c0]);
      }
    }
  }
#pragma unroll
  for (int mi = 0; mi < 2; mi++)
#pragma unroll
    for (int ni = 0; ni < 4; ni++) {
      const int col = n0 + wn + ni * 16 + l16;
      const float bv = bias[col];
#pragma unroll
      for (int r = 0; r < 4; r++)
        Cs[(size_t)(m0 + wm + mi * 16 + quad * 4 + r) * N + col] =
            f2bf(acc[mi][ni][r] + bv);
    }
}

// ---------------- bf16 GEMM, 64x128 tile, ring-4, f32 out (o-proj) ----------------
__global__ __launch_bounds__(256) void gemm_db_kernel(const short* __restrict__ A,
                                                      const short* __restrict__ B,
                                                      float* __restrict__ C, int N,
                                                      int gx, int gy, int P) {
  __shared__ __align__(16) short As[4][64 * 32];
  __shared__ __align__(16) short Bs[4][128 * 32];
  const int bid = blockIdx.x;
  const int xcd = bid & 7, idx = bid >> 3;
  const int colsPerX = gx >> 1, rowsPerX = gy >> 2;
  const int xt = (xcd & 1) * colsPerX + idx % colsPerX;
  const int yt = (xcd >> 1) * rowsPerX + idx / colsPerX;
  const int tid = threadIdx.x;
  const int lane = tid & 63, wave = tid >> 6;
  const int quad = lane >> 4, l16 = lane & 15;
  const int m0 = yt * 64, n0 = xt * 128;
  const int wm = (wave >> 1) * 32, wn = (wave & 1) * 64;
  const int r0 = tid >> 2, c0 = (tid & 3) * 8;
  const int ca = ((tid & 3) ^ ((r0 >> 1) & 3)) * 8;
  const size_t arow = (size_t)(m0 + r0) * 2048;
  const size_t brow0 = (size_t)(n0 + r0) * 2048, brow1 = (size_t)(n0 + r0 + 64) * 2048;
  f32x4 acc[2][4];
#pragma unroll
  for (int mi = 0; mi < 2; mi++)
#pragma unroll
    for (int ni = 0; ni < 4; ni++) acc[mi][ni] = (f32x4){0.f, 0.f, 0.f, 0.f};

#pragma unroll
  for (int st = 0; st < 4; st++) {
    const int kk = st * 32 + ca;
    GLD_LDS16(&A[arow + kk], &As[st][r0 * 32 + c0]);
    GLD_LDS16(&B[brow0 + kk], &Bs[st][r0 * 32 + c0]);
    GLD_LDS16(&B[brow1 + kk], &Bs[st][(r0 + 64) * 32 + c0]);
  }

  const int sx = (l16 >> 1) & 3;
  for (int p = 0; p < P; p++) {
    if (p < P - 1) {
      __asm__ volatile("s_waitcnt vmcnt(6)" ::: "memory");
    } else {
      __asm__ volatile("s_waitcnt vmcnt(0)" ::: "memory");
    }
    raw_barrier();
#pragma unroll
    for (int j = 0; j < 2; j++) {
      const int cur = (2 * p + j) & 3;
      bf16x8 af[2], bfr[4];
#pragma unroll
      for (int mi = 0; mi < 2; mi++)
        af[mi] = *(const bf16x8*)&As[cur][(wm + mi * 16 + l16) * 32 + ((quad ^ sx) * 8)];
#pragma unroll
      for (int ni = 0; ni < 4; ni++)
        bfr[ni] = *(const bf16x8*)&Bs[cur][(wn + ni * 16 + l16) * 32 + ((quad ^ sx) * 8)];
#pragma unroll
      for (int mi = 0; mi < 2; mi++)
#pragma unroll
        for (int ni = 0; ni < 4; ni++)
          acc[mi][ni] = MFMA16(af[mi], bfr[ni], acc[mi][ni]);
    }
    __asm__ volatile("s_waitcnt lgkmcnt(0)" ::: "memory");
    raw_barrier();
    if (p < P - 2) {
#pragma unroll
      for (int j = 0; j < 2; j++) {
        const int st = 2 * p + 4 + j;
        const int slot = st & 3;
        const int kk = st * 32 + ca;
        GLD_LDS16(&A[arow + kk], &As[slot][r0 * 32 + c0]);
        GLD_LDS16(&B[brow0 + kk], &Bs[slot][r0 * 32 + c0]);
        GLD_LDS16(&B[brow1 + kk], &Bs[slot][(r0 + 64) * 32 + c0]);
      }
    }
  }
#pragma unroll
  for (int mi = 0; mi < 2; mi++)
#pragma unroll
    for (int ni = 0; ni < 4; ni++)
#pragma unroll
      for (int r = 0; r < 4; r++)
        C[(size_t)(m0 + wm + mi * 16 + quad * 4 + r) * N + n0 + wn + ni * 16 + l16] =
            acc[mi][ni][r];
}

// ---------------- merged: Q/K post (rmsnorm+rope+mask) AND V mask+transpose ------
__global__ __launch_bounds__(256) void postv_kernel(
    const short* __restrict__ qkvb, const float* __restrict__ qg,
    const float* __restrict__ kg, const float* __restrict__ cosb,
    const float* __restrict__ sinb, const float* __restrict__ maskp,
    short* __restrict__ qo, short* __restrict__ ko, short* __restrict__ vtb) {
  __shared__ short t[32][33];
  const int bid = blockIdx.x;
  if (bid < 9216) {
    const int rid = bid * 4 + (threadIdx.x >> 6);
    const int lane = threadIdx.x & 63;
    const int slot = rid >> 11;
    const int bs = rid & 2047;
    const int b = bs >> 10, s = bs & 1023;
    const short* row = qkvb + (size_t)bs * 2560;
    int off;
    const float* gamma;
    if (slot < 16) { off = slot * 128; gamma = qg; }
    else { off = 2048 + (slot - 16) * 128; gamma = kg; }
    float v0 = bf2f(row[off + lane]);
    float v1 = bf2f(row[off + 64 + lane]);
    float ss = v0 * v0 + v1 * v1;
#pragma unroll
    for (int o = 1; o < 64; o <<= 1) ss += __shfl_xor(ss, o);
    float r = rsqrtf(ss * (1.0f / 128.0f) + 1e-6f);
    v0 = gamma[lane] * v0 * r;
    v1 = gamma[64 + lane] * v1 * r;
    int sel = (lane < 16) ? 0 : (lane < 40) ? 1 : 2;
    size_t ci = ((size_t)(sel * 2 + b) * 1024 + s) * 128 + lane;
    float c0 = cosb[ci], s0 = sinb[ci], c1 = cosb[ci + 64], s1 = sinb[ci + 64];
    float o0 = v0 * c0 - v1 * s0;
    float o1 = v1 * c1 + v0 * s1;
    if (slot >= 16) { float mk = maskp[bs]; o0 *= mk; o1 *= mk; }
    size_t oidx;
    short* optr;
    if (slot < 16) { oidx = (((size_t)(b * 16 + slot) * 1024) + s) * 128; optr = qo; }
    else { oidx = (((size_t)(b * 2 + (slot - 16)) * 1024) + s) * 128; optr = ko; }
    optr[oidx + lane] = f2bf(o0);
    optr[oidx + 64 + lane] = f2bf(o1);
    return;
  }
  const int b2 = bid - 9216;
  const int d0 = (b2 & 3) * 32;
  const int s0 = ((b2 >> 2) & 31) * 32;
  const int bz = b2 >> 7;
  const int bq = bz >> 1, kv = bz & 1;
  const int tx = threadIdx.x & 31;
  const int ty = threadIdx.x >> 5;
#pragma unroll
  for (int i = 0; i < 4; i++) {
    int s = s0 + ty + i * 8;
    size_t qi = ((size_t)(bq * 1024 + s)) * 2560 + 2304 + kv * 128 + d0 + tx;
    float val = bf2f(qkvb[qi]);
    t[ty + i * 8][tx] = f2bf(val * maskp[bq * 1024 + s]);
  }
  __syncthreads();
#pragma unroll
  for (int i = 0; i < 4; i++)
    vtb[((size_t)bz * 128 + d0 + ty + i * 8) * 1024 + s0 + tx] = t[tx][ty + i * 8];
}

// ---------------- flash attention: one block per q-tile, direct output write ----------------
// Fixed-shift softmax (p = exp(s*scale - 12)) needs no running-max rescale, so a single
// block can walk all causal K-tiles and normalize once at the end -- the 40-partials
// po/pml round-trip (~50MB) and the combine kernel are gone. qt = 15 - blockIdx.x puts
// the 16-step blocks first (makespan ~= balanced 17 steps/CU at 512 blocks, 2/CU).
__global__ __launch_bounds__(256) void attn_kernel(const short* __restrict__ Q,
                                                   const short* __restrict__ K,
                                                   const short* __restrict__ Vt_g,
                                                   short* __restrict__ attn) {
  const int qt = 15 - (int)blockIdx.x;
  const int h = blockIdx.y;
  const int b = blockIdx.z;
  const int nsteps = qt + 1;

  const int kv = h >> 3;
  const int tid = threadIdx.x;
  const int wave = tid >> 6, lane = tid & 63;
  const int quad = lane >> 4, l16 = lane & 15;
  __shared__ __align__(16) short Ks[2][64 * 128];
  __shared__ __align__(16) short Vs[2][128 * 64];
  __shared__ __align__(16) short Ps[4][16 * 72];

  const size_t qoff = (((size_t)(b * 16 + h) * 1024) + qt * 64 + wave * 16 + l16) * 128;
  bf16x8 aq[4];
#pragma unroll
  for (int kk = 0; kk < 4; kk++) aq[kk] = *(const bf16x8*)&Q[qoff + kk * 32 + quad * 8];

  f32x4 o[8];
#pragma unroll
  for (int i = 0; i < 8; i++) o[i] = (f32x4){0.f, 0.f, 0.f, 0.f};
  float l[4] = {0.f, 0.f, 0.f, 0.f};
  const int qrow0 = qt * 64 + wave * 16 + quad * 4;
  const size_t koff = ((size_t)(b * 2 + kv) * 1024) * 128;
  const size_t voff = koff;
  const float scale = 0.08838834764831845f;  // 1/sqrt(128)

#define STAGE_KV(bf, ks0)                                                          \
  {                                                                                \
    _Pragma("unroll") for (int it = 0; it < 4; it++) {                             \
      const int c = it * 256 + tid;                                                \
      const int row = c >> 4, sl = c & 15;                                         \
      GLD_LDS16(&K[koff + (size_t)((ks0) + row) * 128 + ((sl ^ (row & 7)) * 8)],   \
                &Ks[bf][c * 8]);                                                   \
      const int d = c >> 3, sv = c & 7;                                            \
      GLD_LDS16(&Vt_g[voff + (size_t)d * 1024 + (ks0) + ((sv ^ (d & 7)) * 8)],     \
                &Vs[bf][c * 8]);                                                   \
    }                                                                              \
  }

  STAGE_KV(0, 0);

  for (int st = 0; st < nsteps; st++) {
    __asm__ volatile("s_waitcnt vmcnt(0)" ::: "memory");
    raw_barrier();
    if (st + 1 < nsteps) { STAGE_KV((st + 1) & 1, (st + 1) * 64); }
    const int cb = st & 1;
    const int ks0 = st * 64;
    f32x4 sc[4];
#pragma unroll
    for (int nt = 0; nt < 4; nt++) sc[nt] = (f32x4){0.f, 0.f, 0.f, 0.f};
    __builtin_amdgcn_s_setprio(1);
#pragma unroll
    for (int nt = 0; nt < 4; nt++) {
      const int rr = nt * 16 + l16;
#pragma unroll
      for (int kk = 0; kk < 4; kk++) {
        bf16x8 bk = *(const bf16x8*)&Ks[cb][rr * 128 + (((kk * 4 + quad) ^ (rr & 7)) * 8)];
        sc[nt] = MFMA16(aq[kk], bk, sc[nt]);
      }
    }
    __builtin_amdgcn_s_setprio(0);
    // fixed-shift softmax weights: p = exp(s*scale - 12), causal-masked to 0
    short* P = &Ps[wave][0];
#pragma unroll
    for (int nt = 0; nt < 4; nt++) {
      const int kcol = ks0 + nt * 16 + l16;
#pragma unroll
      for (int r = 0; r < 4; r++) {
        float p = (kcol > qrow0 + r) ? 0.f : __expf(fmaf(sc[nt][r], scale, -12.0f));
        l[r] += p;
        P[(quad * 4 + r) * 72 + nt * 16 + l16] = f2bf(p);
      }
    }
    __asm__ volatile("s_waitcnt lgkmcnt(0)" ::: "memory");
    bf16x8 pa0 = *(const bf16x8*)&P[l16 * 72 + quad * 8];
    bf16x8 pa1 = *(const bf16x8*)&P[l16 * 72 + 32 + quad * 8];
    __builtin_amdgcn_s_setprio(1);
#pragma unroll
    for (int nt = 0; nt < 8; nt++) {
      const int rr = nt * 16 + l16;
      bf16x8 bv0 = *(const bf16x8*)&Vs[cb][rr * 64 + ((quad ^ (rr & 7)) * 8)];
      bf16x8 bv1 = *(const bf16x8*)&Vs[cb][rr * 64 + (((4 + quad) ^ (rr & 7)) * 8)];
      o[nt] = MFMA16(pa0, bv0, o[nt]);
      o[nt] = MFMA16(pa1, bv1, o[nt]);
    }
    __builtin_amdgcn_s_setprio(0);
  }
#undef STAGE_KV
  // row-sum reduce across the 16 column-lanes, then normalize and write final output
#pragma unroll
  for (int off = 1; off < 16; off <<= 1)
#pragma unroll
    for (int r = 0; r < 4; r++) l[r] += __shfl_xor(l[r], off);
  float inv[4];
#pragma unroll
  for (int r = 0; r < 4; r++) inv[r] = 1.f / l[r];
  const int lrow = wave * 16 + quad * 4;
  short* dst = attn + ((size_t)(b * 1024 + qt * 64 + lrow)) * 2048 + h * 128;
#pragma unroll
  for (int nt = 0; nt < 8; nt++)
#pragma unroll
    for (int r = 0; r < 4; r++)
      dst[(size_t)r * 2048 + nt * 16 + l16] = f2bf(o[nt][r] * inv[r]);
}

extern "C" void kernel_launch(void* const* d_in, const int* in_sizes, int n_in,
                              void* d_out, int out_size, void* d_ws, size_t ws_size,
                              hipStream_t stream) {
  const float* x = (const float*)d_in[0];
  const float* cosb = (const float*)d_in[1];
  const float* sinb = (const float*)d_in[2];
  const float* mask = (const float*)d_in[3];
  const float* q_w = (const float*)d_in[4];
  const float* q_b = (const float*)d_in[5];
  const float* k_w = (const float*)d_in[6];
  const float* k_b = (const float*)d_in[7];
  const float* v_w = (const float*)d_in[8];
  const float* v_b = (const float*)d_in[9];
  const float* qg = (const float*)d_in[10];
  const float* kg = (const float*)d_in[11];
  const float* o_w = (const float*)d_in[12];
  float* out = (float*)d_out;

  char* ws = (char*)d_ws;
  short* wo_t = (short*)(ws);                              // [0,8) MB
  short* wqkv_t = (short*)(ws + ((size_t)8 << 20));        // [8,18.4) MB (dead after gemm)
  short* attn = (short*)(ws + ((size_t)9 << 20));          // aliases wqkv_t (after gemm)
  short* xb = (short*)(ws + ((size_t)18 << 20));           // [18,26.4) MB
  short* qb = xb;
  short* kb = (short*)(ws + ((size_t)46 << 20));           // [46,47)
  short* vtb = (short*)(ws + ((size_t)47 << 20));          // [47,48)
  short* qkvb = (short*)(ws + ((size_t)48 << 20));         // [48,58) MB bf16 qkv
  float* biasAll = (float*)(ws + ((size_t)68 << 20));      // 10 KB fused bias

  prep_kernel<<<6401, 256, 0, stream>>>(x, q_w, k_w, v_w, o_w, q_b, k_b, v_b, xb,
                                        wqkv_t, wo_t, biasAll);
  gemm_qkv_kernel<<<640, 256, 0, stream>>>(xb, wqkv_t, qkvb, biasAll, 2560, 20, 32, 32);
  postv_kernel<<<9728, 256, 0, stream>>>(qkvb, qg, kg, cosb, sinb, mask, qb, kb, vtb);
  attn_kernel<<<dim3(16, 16, 2), 256, 0, stream>>>(qb, kb, vtb, attn);
  gemm_db_kernel<<<512, 256, 0, stream>>>(attn, wo_t, out, 2048, 16, 32, 32);
}